// Round 1
// baseline (225.946 us; speedup 1.0000x reference)
//
#include <hip/hip_runtime.h>
#include <hip/hip_bf16.h>

// Problem constants: L=512, B=2, D=256, C=128, O=64
#define LL 512
#define BB 2
#define DD 256
#define CC 128
#define OO 64

typedef __attribute__((ext_vector_type(8))) short bf16x8;  // 8 bf16 (4 VGPRs)
typedef __attribute__((ext_vector_type(4))) float f32x4;   // 4 fp32 acc

__device__ __forceinline__ short f2bf(float v) {
    __hip_bfloat16 h = __float2bfloat16(v);
    return *reinterpret_cast<short*>(&h);
}

__device__ __forceinline__ float wave_reduce_sum(float v) {
#pragma unroll
    for (int off = 32; off > 0; off >>= 1)
        v += __shfl_down(v, off, 64);
    return v;
}

// One block per (b, l): LayerNorm of x[l,b,:], then
//   a[c]    = LN(x).w1[:,c] + b1[c]      -> a_ws (fp32, for Wl build in main)
//   b[c]    = LN(x).w2[:,c] + b2[c]      -> bact (bf16, MFMA A-operand)
//   a4b3[o] = a.w4[:,o] + b3[o]          -> fp32 (epilogue bias)
// Blocks 0..63 additionally transpose w3 -> w3t, w4 -> w4t (one elem/thread).
__global__ __launch_bounds__(256) void prep_kernel(
    const float* __restrict__ x,
    const float* __restrict__ gamma,
    const float* __restrict__ beta,
    const float* __restrict__ w1, const float* __restrict__ b1,
    const float* __restrict__ w2, const float* __restrict__ b2,
    const float* __restrict__ w4, const float* __restrict__ b3,
    const float* __restrict__ w3,
    float* __restrict__ a_ws, __hip_bfloat16* __restrict__ bact,
    float* __restrict__ a4b3_ws,
    float* __restrict__ w3t_ws, float* __restrict__ w4t_ws)
{
    const int blk = blockIdx.x;           // b*LL + l
    const int b = blk >> 9;
    const int l = blk & (LL - 1);
    const int t = threadIdx.x;            // 0..255 == d index

    __shared__ float ylds[DD];
    __shared__ float ashare[CC];
    __shared__ float red[8];

    // --- w3/w4 transpose: one element per thread across blocks 0..63 ---
    {
        const int idx = blk * 256 + t;
        if (idx < 2 * CC * OO) {
            const float* src = (idx < CC * OO) ? w3 : w4;
            float* dst = (idx < CC * OO) ? w3t_ws : w4t_ws;
            const int i = idx & (CC * OO - 1);   // i = c*OO + o (coalesced read)
            const int o = i & (OO - 1);
            const int c = i >> 6;
            dst[o * CC + c] = src[i];
        }
    }

    // --- LayerNorm ---
    // x is (L, B, D)
    float xv = x[(l * BB + b) * DD + t];
    float s = wave_reduce_sum(xv);
    if ((t & 63) == 0) red[t >> 6] = s;
    __syncthreads();
    float mu = (red[0] + red[1] + red[2] + red[3]) * (1.0f / DD);
    float xc = xv - mu;
    float s2 = wave_reduce_sum(xc * xc);
    if ((t & 63) == 0) red[4 + (t >> 6)] = s2;
    __syncthreads();
    float var = (red[4] + red[5] + red[6] + red[7]) * (1.0f / DD);
    float y = xc * rsqrtf(var + 1e-5f) * gamma[t] + beta[t];
    ylds[t] = y;
    __syncthreads();

    // a (threads 0..127) and b (threads 128..255) projections
    {
        const int c = t & (CC - 1);
        const float* w = (t < CC) ? w1 : w2;
        float acc = (t < CC) ? b1[c] : b2[c];
#pragma unroll 16
        for (int d = 0; d < DD; ++d)
            acc = fmaf(ylds[d], w[d * CC + c], acc);
        if (t < CC) {
            a_ws[(b * LL + l) * CC + c] = acc;
            ashare[c] = acc;
        } else {
            bact[(b * LL + l) * CC + c] = __float2bfloat16(acc);
        }
    }
    __syncthreads();

    // a4b3[o] = a . w4[:,o] + b3[o]  (threads 0..63)
    if (t < OO) {
        float acc = b3[t];
#pragma unroll 16
        for (int c = 0; c < CC; ++c)
            acc = fmaf(ashare[c], w4[c * OO + t], acc);
        a4b3_ws[(b * LL + l) * OO + t] = acc;
    }
}

// One block per (b, l, m-half). 4 waves; wave w computes out[b, l, mh*256+w*64 .. +64, :].
// B-operand built PER-LANE IN REGISTERS (no LDS, no __syncthreads):
//   Wl[c][o] = bf16(a[l,c]*w3[c,o] - w4[c,o])
// which folds the entire  -b4[m,o] = -(b@w4)[m,o]  term into the GEMM
// (same A-operand bact), so the epilogue is just  + a4b3[l,o].
__global__ __launch_bounds__(256, 3) void main_kernel(
    const float* __restrict__ a_ws, const __hip_bfloat16* __restrict__ bact,
    const float* __restrict__ a4b3_ws,
    const float* __restrict__ w3t, const float* __restrict__ w4t,
    float* __restrict__ out)
{
    const int bid = blockIdx.x;           // b*1024 + l*2 + mh
    const int mh = bid & 1;
    const int l  = (bid >> 1) & (LL - 1);
    const int b  = bid >> 10;
    const int t  = threadIdx.x;
    const int wave = t >> 6;
    const int lane = t & 63;
    const int ln = lane & 15;             // col within 16x16 tile
    const int q  = lane >> 4;             // quad

    const int mbase = mh * 256 + wave * 64;

    const float* arow = a_ws + (b * LL + l) * CC;      // a[l, :] fp32
    // A-frag base: lane (ln,q) holds Bact[m = mbase+mt*16+ln][c = ks*32+q*8 .. +8]
    const short* abase = (const short*)bact + ((size_t)(b * LL + mbase + ln)) * CC + q * 8;

    // epilogue bias, loaded early (independent of the GEMM)
    float a4v[4];
    const float* a4p = a4b3_ws + (b * LL + l) * OO;
#pragma unroll
    for (int ot = 0; ot < 4; ++ot)
        a4v[ot] = a4p[ot * 16 + ln];

    f32x4 acc[4][4];
#pragma unroll
    for (int mt = 0; mt < 4; ++mt)
#pragma unroll
        for (int ot = 0; ot < 4; ++ot)
            acc[mt][ot] = (f32x4){0.f, 0.f, 0.f, 0.f};

#pragma unroll
    for (int ks = 0; ks < 4; ++ks) {
        const int cb = ks * 32 + q * 8;   // this lane's K-slice base

        // a[l, cb..cb+8] (uniform across ln within a q-group; cache-served)
        const float4 av0 = *(const float4*)(arow + cb);
        const float4 av1 = *(const float4*)(arow + cb + 4);

        bf16x8 af[4];
#pragma unroll
        for (int mt = 0; mt < 4; ++mt)
            af[mt] = *(const bf16x8*)(abase + mt * (16 * CC) + ks * 32);

#pragma unroll
        for (int ot = 0; ot < 4; ++ot) {
            const int o = ot * 16 + ln;
            const float* w3p = w3t + o * CC + cb;
            const float* w4p = w4t + o * CC + cb;
            const float4 x0 = *(const float4*)(w3p);
            const float4 x1 = *(const float4*)(w3p + 4);
            const float4 y0 = *(const float4*)(w4p);
            const float4 y1 = *(const float4*)(w4p + 4);

            bf16x8 bfr;
            bfr[0] = f2bf(fmaf(av0.x, x0.x, -y0.x));
            bfr[1] = f2bf(fmaf(av0.y, x0.y, -y0.y));
            bfr[2] = f2bf(fmaf(av0.z, x0.z, -y0.z));
            bfr[3] = f2bf(fmaf(av0.w, x0.w, -y0.w));
            bfr[4] = f2bf(fmaf(av1.x, x1.x, -y1.x));
            bfr[5] = f2bf(fmaf(av1.y, x1.y, -y1.y));
            bfr[6] = f2bf(fmaf(av1.z, x1.z, -y1.z));
            bfr[7] = f2bf(fmaf(av1.w, x1.w, -y1.w));

#pragma unroll
            for (int mt = 0; mt < 4; ++mt)
                acc[mt][ot] = __builtin_amdgcn_mfma_f32_16x16x32_bf16(
                    af[mt], bfr, acc[mt][ot], 0, 0, 0);
        }
    }

    // Epilogue: out[b,l,m,o] = acc + a4b3[b,l,o]
    // C/D layout: col = lane&15, row = q*4 + reg   [verified m89/m91]
#pragma unroll
    for (int mt = 0; mt < 4; ++mt) {
        const int mrow = mbase + mt * 16 + q * 4;
        float* outp = out + (((size_t)(b * LL + l)) * LL + mrow) * OO + ln;
#pragma unroll
        for (int ot = 0; ot < 4; ++ot) {
#pragma unroll
            for (int r = 0; r < 4; ++r) {
                outp[r * OO + ot * 16] = acc[mt][ot][r] + a4v[ot];
            }
        }
    }
}

extern "C" void kernel_launch(void* const* d_in, const int* in_sizes, int n_in,
                              void* d_out, int out_size, void* d_ws, size_t ws_size,
                              hipStream_t stream) {
    const float* x     = (const float*)d_in[0];
    const float* gamma = (const float*)d_in[1];
    const float* beta  = (const float*)d_in[2];
    const float* w1    = (const float*)d_in[3];
    const float* b1    = (const float*)d_in[4];
    const float* w2    = (const float*)d_in[5];
    const float* b2    = (const float*)d_in[6];
    const float* w3    = (const float*)d_in[7];
    const float* b3    = (const float*)d_in[8];
    const float* w4    = (const float*)d_in[9];
    float* out = (float*)d_out;

    char* ws = (char*)d_ws;
    float* a_ws            = (float*)ws;                       // B*L*C fp32  = 512 KB
    __hip_bfloat16* bact   = (__hip_bfloat16*)(ws + 512*1024); // B*L*C bf16  = 256 KB
    float* a4b3_ws         = (float*)(ws + 768*1024);          // B*L*O fp32  = 256 KB
    float* w3t_ws          = (float*)(ws + 1024*1024);         // O*C fp32    = 32 KB
    float* w4t_ws          = (float*)(ws + 1024*1024 + 32*1024); // O*C fp32  = 32 KB

    prep_kernel<<<BB * LL, 256, 0, stream>>>(x, gamma, beta, w1, b1, w2, b2,
                                             w4, b3, w3,
                                             a_ws, bact, a4b3_ws, w3t_ws, w4t_ws);
    main_kernel<<<BB * LL * 2, 256, 0, stream>>>(a_ws, bact, a4b3_ws,
                                                 w3t_ws, w4t_ws, out);
}

// Round 2
// 225.028 us; speedup vs baseline: 1.0041x; 1.0041x over previous
//
#include <hip/hip_runtime.h>
#include <hip/hip_bf16.h>

// Problem constants: L=512, B=2, D=256, C=128, O=64
#define LL 512
#define BB 2
#define DD 256
#define CC 128
#define OO 64

typedef __attribute__((ext_vector_type(8))) short bf16x8;  // 8 bf16 (4 VGPRs)
typedef __attribute__((ext_vector_type(4))) float f32x4;   // 4 fp32 acc

__device__ __forceinline__ short f2bf(float v) {
    __hip_bfloat16 h = __float2bfloat16(v);
    return *reinterpret_cast<short*>(&h);
}

__device__ __forceinline__ float wave_reduce_sum(float v) {
#pragma unroll
    for (int off = 32; off > 0; off >>= 1)
        v += __shfl_down(v, off, 64);
    return v;
}

// One block per (b, l): LayerNorm of x[l,b,:], then
//   a[c]    = LN(x).w1[:,c] + b1[c]      -> a_ws (fp32, for Wl build in main)
//   b[c]    = LN(x).w2[:,c] + b2[c]      -> bact (bf16, MFMA A-operand)
//   a4b3[o] = a.w4[:,o] + b3[o]          -> fp32 (epilogue bias)
// Blocks 0..63 additionally transpose w3 -> w3t, w4 -> w4t (one elem/thread).
__global__ __launch_bounds__(256) void prep_kernel(
    const float* __restrict__ x,
    const float* __restrict__ gamma,
    const float* __restrict__ beta,
    const float* __restrict__ w1, const float* __restrict__ b1,
    const float* __restrict__ w2, const float* __restrict__ b2,
    const float* __restrict__ w4, const float* __restrict__ b3,
    const float* __restrict__ w3,
    float* __restrict__ a_ws, __hip_bfloat16* __restrict__ bact,
    float* __restrict__ a4b3_ws,
    float* __restrict__ w3t_ws, float* __restrict__ w4t_ws)
{
    const int blk = blockIdx.x;           // b*LL + l
    const int b = blk >> 9;
    const int l = blk & (LL - 1);
    const int t = threadIdx.x;            // 0..255 == d index

    __shared__ float ylds[DD];
    __shared__ float ashare[CC];
    __shared__ float red[8];

    // --- w3/w4 transpose: one element per thread across blocks 0..63 ---
    {
        const int idx = blk * 256 + t;
        if (idx < 2 * CC * OO) {
            const float* src = (idx < CC * OO) ? w3 : w4;
            float* dst = (idx < CC * OO) ? w3t_ws : w4t_ws;
            const int i = idx & (CC * OO - 1);   // i = c*OO + o (coalesced read)
            const int o = i & (OO - 1);
            const int c = i >> 6;
            dst[o * CC + c] = src[i];
        }
    }

    // --- LayerNorm ---
    // x is (L, B, D)
    float xv = x[(l * BB + b) * DD + t];
    float s = wave_reduce_sum(xv);
    if ((t & 63) == 0) red[t >> 6] = s;
    __syncthreads();
    float mu = (red[0] + red[1] + red[2] + red[3]) * (1.0f / DD);
    float xc = xv - mu;
    float s2 = wave_reduce_sum(xc * xc);
    if ((t & 63) == 0) red[4 + (t >> 6)] = s2;
    __syncthreads();
    float var = (red[4] + red[5] + red[6] + red[7]) * (1.0f / DD);
    float y = xc * rsqrtf(var + 1e-5f) * gamma[t] + beta[t];
    ylds[t] = y;
    __syncthreads();

    // a (threads 0..127) and b (threads 128..255) projections
    {
        const int c = t & (CC - 1);
        const float* w = (t < CC) ? w1 : w2;
        float acc = (t < CC) ? b1[c] : b2[c];
#pragma unroll 16
        for (int d = 0; d < DD; ++d)
            acc = fmaf(ylds[d], w[d * CC + c], acc);
        if (t < CC) {
            a_ws[(b * LL + l) * CC + c] = acc;
            ashare[c] = acc;
        } else {
            bact[(b * LL + l) * CC + c] = __float2bfloat16(acc);
        }
    }
    __syncthreads();

    // a4b3[o] = a . w4[:,o] + b3[o]  (threads 0..63)
    if (t < OO) {
        float acc = b3[t];
#pragma unroll 16
        for (int c = 0; c < CC; ++c)
            acc = fmaf(ashare[c], w4[c * OO + t], acc);
        a4b3_ws[(b * LL + l) * OO + t] = acc;
    }
}

// One block per (b, l, m-half). 4 waves; wave w computes out[b, l, mh*256+w*64 .. +64, :].
// B-operand built PER-LANE IN REGISTERS (no block-wide LDS staging, no __syncthreads):
//   Wl[c][o] = bf16(a[l,c]*w3[c,o] - w4[c,o])
// which folds the entire  -b4[m,o] = -(b@w4)[m,o]  term into the GEMM
// (same A-operand bact), so the epilogue is just  + a4b3[l,o].
//
// Epilogue: MFMA C/D layout (col=ln, row=q*4+r) makes direct stores 4x64B
// scattered segments -> store-instruction-rate limited (R1 counters: 1.5 TB/s
// vs fill's 6.6 TB/s at the SAME wave-store-instruction count). Fix: stage
// each 16x64 tile through per-wave LDS (stride 68 -> 2-way banks = free),
// read back lane-linear, store wave-contiguous 1KB dwordx4. 64 -> 16 store
// instrs per wave.
__global__ __launch_bounds__(256, 3) void main_kernel(
    const float* __restrict__ a_ws, const __hip_bfloat16* __restrict__ bact,
    const float* __restrict__ a4b3_ws,
    const float* __restrict__ w3t, const float* __restrict__ w4t,
    float* __restrict__ out)
{
    const int bid = blockIdx.x;           // b*1024 + l*2 + mh
    const int mh = bid & 1;
    const int l  = (bid >> 1) & (LL - 1);
    const int b  = bid >> 10;
    const int t  = threadIdx.x;
    const int wave = t >> 6;
    const int lane = t & 63;
    const int ln = lane & 15;             // col within 16x16 tile
    const int q  = lane >> 4;             // quad

    const int mbase = mh * 256 + wave * 64;

    const float* arow = a_ws + (b * LL + l) * CC;      // a[l, :] fp32
    // A-frag base: lane (ln,q) holds Bact[m = mbase+mt*16+ln][c = ks*32+q*8 .. +8]
    const short* abase = (const short*)bact + ((size_t)(b * LL + mbase + ln)) * CC + q * 8;

    // epilogue bias, loaded early (independent of the GEMM)
    float a4v[4];
    const float* a4p = a4b3_ws + (b * LL + l) * OO;
#pragma unroll
    for (int ot = 0; ot < 4; ++ot)
        a4v[ot] = a4p[ot * 16 + ln];

    f32x4 acc[4][4];
#pragma unroll
    for (int mt = 0; mt < 4; ++mt)
#pragma unroll
        for (int ot = 0; ot < 4; ++ot)
            acc[mt][ot] = (f32x4){0.f, 0.f, 0.f, 0.f};

#pragma unroll
    for (int ks = 0; ks < 4; ++ks) {
        const int cb = ks * 32 + q * 8;   // this lane's K-slice base

        // a[l, cb..cb+8] (uniform across ln within a q-group; cache-served)
        const float4 av0 = *(const float4*)(arow + cb);
        const float4 av1 = *(const float4*)(arow + cb + 4);

        bf16x8 af[4];
#pragma unroll
        for (int mt = 0; mt < 4; ++mt)
            af[mt] = *(const bf16x8*)(abase + mt * (16 * CC) + ks * 32);

#pragma unroll
        for (int ot = 0; ot < 4; ++ot) {
            const int o = ot * 16 + ln;
            const float* w3p = w3t + o * CC + cb;
            const float* w4p = w4t + o * CC + cb;
            const float4 x0 = *(const float4*)(w3p);
            const float4 x1 = *(const float4*)(w3p + 4);
            const float4 y0 = *(const float4*)(w4p);
            const float4 y1 = *(const float4*)(w4p + 4);

            bf16x8 bfr;
            bfr[0] = f2bf(fmaf(av0.x, x0.x, -y0.x));
            bfr[1] = f2bf(fmaf(av0.y, x0.y, -y0.y));
            bfr[2] = f2bf(fmaf(av0.z, x0.z, -y0.z));
            bfr[3] = f2bf(fmaf(av0.w, x0.w, -y0.w));
            bfr[4] = f2bf(fmaf(av1.x, x1.x, -y1.x));
            bfr[5] = f2bf(fmaf(av1.y, x1.y, -y1.y));
            bfr[6] = f2bf(fmaf(av1.z, x1.z, -y1.z));
            bfr[7] = f2bf(fmaf(av1.w, x1.w, -y1.w));

#pragma unroll
            for (int mt = 0; mt < 4; ++mt)
                acc[mt][ot] = __builtin_amdgcn_mfma_f32_16x16x32_bf16(
                    af[mt], bfr, acc[mt][ot], 0, 0, 0);
        }
    }

    // ---- Epilogue via per-wave LDS transpose -> wave-contiguous 1KB stores ----
    // Per-wave double buffer: 2 x (16 rows x stride 68 floats) = 8704 B/wave.
    // Stride 68: ds_write 2-way banks (free), 16B-aligned float4 reads.
    __shared__ float stile[4][2 * 16 * 68];

    // wave's output region is contiguous: out[b, l, mbase .. mbase+64, 0..64]
    float* outbase = out + (((size_t)(b * LL + l)) * LL + mbase) * OO;

#pragma unroll
    for (int mt = 0; mt < 4; ++mt) {
        float* sw = stile[wave] + (mt & 1) * (16 * 68);
        // stage 16x64 tile, folding the +a4b3 bias
#pragma unroll
        for (int ot = 0; ot < 4; ++ot)
#pragma unroll
            for (int r = 0; r < 4; ++r)
                sw[(q * 4 + r) * 68 + ot * 16 + ln] = acc[mt][ot][r] + a4v[ot];

        // read back lane-linear (wave-private buffer: no __syncthreads, the
        // compiler orders via lgkmcnt), store 4 x dwordx4 = 1KB/instr wave-wide
#pragma unroll
        for (int i = 0; i < 4; ++i) {
            const int idx = i * 64 + lane;       // float4 index within 16x64 tile
            const int row = idx >> 4;
            const int col = (idx & 15) * 4;
            const float4 v = *(const float4*)(sw + row * 68 + col);
            *(float4*)(outbase + (mt * 16 + row) * OO + col) = v;
        }
    }
}

extern "C" void kernel_launch(void* const* d_in, const int* in_sizes, int n_in,
                              void* d_out, int out_size, void* d_ws, size_t ws_size,
                              hipStream_t stream) {
    const float* x     = (const float*)d_in[0];
    const float* gamma = (const float*)d_in[1];
    const float* beta  = (const float*)d_in[2];
    const float* w1    = (const float*)d_in[3];
    const float* b1    = (const float*)d_in[4];
    const float* w2    = (const float*)d_in[5];
    const float* b2    = (const float*)d_in[6];
    const float* w3    = (const float*)d_in[7];
    const float* b3    = (const float*)d_in[8];
    const float* w4    = (const float*)d_in[9];
    float* out = (float*)d_out;

    char* ws = (char*)d_ws;
    float* a_ws            = (float*)ws;                       // B*L*C fp32  = 512 KB
    __hip_bfloat16* bact   = (__hip_bfloat16*)(ws + 512*1024); // B*L*C bf16  = 256 KB
    float* a4b3_ws         = (float*)(ws + 768*1024);          // B*L*O fp32  = 256 KB
    float* w3t_ws          = (float*)(ws + 1024*1024);         // O*C fp32    = 32 KB
    float* w4t_ws          = (float*)(ws + 1024*1024 + 32*1024); // O*C fp32  = 32 KB

    prep_kernel<<<BB * LL, 256, 0, stream>>>(x, gamma, beta, w1, b1, w2, b2,
                                             w4, b3, w3,
                                             a_ws, bact, a4b3_ws, w3t_ws, w4t_ws);
    main_kernel<<<BB * LL * 2, 256, 0, stream>>>(a_ws, bact, a4b3_ws,
                                                 w3t_ws, w4t_ws, out);
}

// Round 3
// 176.633 us; speedup vs baseline: 1.2792x; 1.2740x over previous
//
#include <hip/hip_runtime.h>
#include <hip/hip_bf16.h>

// Problem constants: L=512, B=2, D=256, C=128, O=64
#define LL 512
#define BB 2
#define DD 256
#define CC 128
#define OO 64

typedef __attribute__((ext_vector_type(8))) short bf16x8;  // 8 bf16 (4 VGPRs)
typedef __attribute__((ext_vector_type(4))) float f32x4;   // 4 fp32 acc

__device__ __forceinline__ short f2bf(float v) {
    __hip_bfloat16 h = __float2bfloat16(v);
    return *reinterpret_cast<short*>(&h);
}

__device__ __forceinline__ float wave_reduce_sum(float v) {
#pragma unroll
    for (int off = 32; off > 0; off >>= 1)
        v += __shfl_down(v, off, 64);
    return v;
}

// One block per (b, l): LayerNorm of x[l,b,:], then
//   a[c]    = LN(x).w1[:,c] + b1[c]      -> a_ws (fp32, for Wl build in main)
//   b[c]    = LN(x).w2[:,c] + b2[c]      -> bact (bf16, MFMA A-operand)
//   a4b3[o] = a.w4[:,o] + b3[o]          -> fp32 (epilogue bias)
// Blocks 0..63 additionally transpose w3 -> w3t, w4 -> w4t (one elem/thread).
__global__ __launch_bounds__(256) void prep_kernel(
    const float* __restrict__ x,
    const float* __restrict__ gamma,
    const float* __restrict__ beta,
    const float* __restrict__ w1, const float* __restrict__ b1,
    const float* __restrict__ w2, const float* __restrict__ b2,
    const float* __restrict__ w4, const float* __restrict__ b3,
    const float* __restrict__ w3,
    float* __restrict__ a_ws, __hip_bfloat16* __restrict__ bact,
    float* __restrict__ a4b3_ws,
    float* __restrict__ w3t_ws, float* __restrict__ w4t_ws)
{
    const int blk = blockIdx.x;           // b*LL + l
    const int b = blk >> 9;
    const int l = blk & (LL - 1);
    const int t = threadIdx.x;            // 0..255 == d index

    __shared__ float ylds[DD];
    __shared__ float ashare[CC];
    __shared__ float red[8];

    // --- w3/w4 transpose: one element per thread across blocks 0..63 ---
    {
        const int idx = blk * 256 + t;
        if (idx < 2 * CC * OO) {
            const float* src = (idx < CC * OO) ? w3 : w4;
            float* dst = (idx < CC * OO) ? w3t_ws : w4t_ws;
            const int i = idx & (CC * OO - 1);   // i = c*OO + o (coalesced read)
            const int o = i & (OO - 1);
            const int c = i >> 6;
            dst[o * CC + c] = src[i];
        }
    }

    // --- LayerNorm ---
    // x is (L, B, D)
    float xv = x[(l * BB + b) * DD + t];
    float s = wave_reduce_sum(xv);
    if ((t & 63) == 0) red[t >> 6] = s;
    __syncthreads();
    float mu = (red[0] + red[1] + red[2] + red[3]) * (1.0f / DD);
    float xc = xv - mu;
    float s2 = wave_reduce_sum(xc * xc);
    if ((t & 63) == 0) red[4 + (t >> 6)] = s2;
    __syncthreads();
    float var = (red[4] + red[5] + red[6] + red[7]) * (1.0f / DD);
    float y = xc * rsqrtf(var + 1e-5f) * gamma[t] + beta[t];
    ylds[t] = y;
    __syncthreads();

    // a (threads 0..127) and b (threads 128..255) projections
    {
        const int c = t & (CC - 1);
        const float* w = (t < CC) ? w1 : w2;
        float acc = (t < CC) ? b1[c] : b2[c];
#pragma unroll 16
        for (int d = 0; d < DD; ++d)
            acc = fmaf(ylds[d], w[d * CC + c], acc);
        if (t < CC) {
            a_ws[(b * LL + l) * CC + c] = acc;
            ashare[c] = acc;
        } else {
            bact[(b * LL + l) * CC + c] = __float2bfloat16(acc);
        }
    }
    __syncthreads();

    // a4b3[o] = a . w4[:,o] + b3[o]  (threads 0..63)
    if (t < OO) {
        float acc = b3[t];
#pragma unroll 16
        for (int c = 0; c < CC; ++c)
            acc = fmaf(ashare[c], w4[c * OO + t], acc);
        a4b3_ws[(b * LL + l) * OO + t] = acc;
    }
}

// One block per (b, l, m-half). 4 waves; wave w computes out[b, l, mh*256+w*64 .. +64, :].
//
// R2 post-mortem: stores are NOT the limit (4x fewer store instrs, same 85us).
// All pipes ~95% idle -> latency-bound on the K-loop's w3t/w4t gathers
// (per-lane o-stride 512B -> ~32 cache lines per load instr, 2048 lines/wave)
// with only 80 VGPRs to buffer them. Fix: build the per-l B-matrix
//   Wt[o][c] = bf16(a[l,c]*w3[c,o] - w4[c,o])
// ONCE per block in LDS from coalesced float4 streams, XOR-swizzled
// (granule g' = g ^ (o&15)) so K-loop ds_read_b128 fragments are <=2-way.
// K-loop then touches only LDS + coalesced bact A-frags. LDS 33.8 KB,
// launch_bounds(256,4) -> 4 blocks/CU (16 waves/CU) for latency hiding.
__global__ __launch_bounds__(256, 4) void main_kernel(
    const float* __restrict__ a_ws, const __hip_bfloat16* __restrict__ bact,
    const float* __restrict__ a4b3_ws,
    const float* __restrict__ w3t, const float* __restrict__ w4t,
    float* __restrict__ out)
{
    const int bid = blockIdx.x;           // b*1024 + l*2 + mh
    const int mh = bid & 1;
    const int l  = (bid >> 1) & (LL - 1);
    const int b  = bid >> 10;
    const int t  = threadIdx.x;
    const int wave = t >> 6;
    const int lane = t & 63;
    const int ln = lane & 15;             // col within 16x16 tile
    const int q  = lane >> 4;             // quad

    __shared__ alignas(16) unsigned short Wt[OO * CC];  // 16 KB, swizzled granules
    __shared__ float stile[4][16 * 68];                 // 17.4 KB store staging

    // ---- Build Wt (swizzled): element (o,c) lives at ushort index
    //      o*CC + ((c>>3) ^ (o&15))*8 + (c&7).  Granule = 8 bf16 = 16 B. ----
    const float* arow = a_ws + (b * LL + l) * CC;
    {
        const int g  = t & 15;            // granule index (c-block of 8)
        const int orr = t >> 4;           // 0..15
        const int c0 = g * 8;
        const float4 a0 = *(const float4*)(arow + c0);
        const float4 a1 = *(const float4*)(arow + c0 + 4);
#pragma unroll
        for (int i = 0; i < 4; ++i) {
            const int o = i * 16 + orr;
            const float* p3 = w3t + o * CC + c0;   // coalesced: 16 lanes span a row
            const float* p4 = w4t + o * CC + c0;
            const float4 x0 = *(const float4*)(p3);
            const float4 x1 = *(const float4*)(p3 + 4);
            const float4 y0 = *(const float4*)(p4);
            const float4 y1 = *(const float4*)(p4 + 4);
            bf16x8 v;
            v[0] = f2bf(fmaf(a0.x, x0.x, -y0.x));
            v[1] = f2bf(fmaf(a0.y, x0.y, -y0.y));
            v[2] = f2bf(fmaf(a0.z, x0.z, -y0.z));
            v[3] = f2bf(fmaf(a0.w, x0.w, -y0.w));
            v[4] = f2bf(fmaf(a1.x, x1.x, -y1.x));
            v[5] = f2bf(fmaf(a1.y, x1.y, -y1.y));
            v[6] = f2bf(fmaf(a1.z, x1.z, -y1.z));
            v[7] = f2bf(fmaf(a1.w, x1.w, -y1.w));
            *(bf16x8*)(&Wt[o * CC + ((g ^ (o & 15)) * 8)]) = v;
        }
    }

    const int mbase = mh * 256 + wave * 64;
    // A-frag base: lane (ln,q) holds Bact[m = mbase+mt*16+ln][c = ks*32+q*8 .. +8]
    const short* abase = (const short*)bact + ((size_t)(b * LL + mbase + ln)) * CC + q * 8;

    // epilogue bias, loaded early (independent of the GEMM)
    float a4v[4];
    const float* a4p = a4b3_ws + (b * LL + l) * OO;
#pragma unroll
    for (int ot = 0; ot < 4; ++ot)
        a4v[ot] = a4p[ot * 16 + ln];

    f32x4 acc[4][4];
#pragma unroll
    for (int mt = 0; mt < 4; ++mt)
#pragma unroll
        for (int ot = 0; ot < 4; ++ot)
            acc[mt][ot] = (f32x4){0.f, 0.f, 0.f, 0.f};

    __syncthreads();

#pragma unroll
    for (int ks = 0; ks < 4; ++ks) {
        bf16x8 af[4], bfr[4];
#pragma unroll
        for (int mt = 0; mt < 4; ++mt)
            af[mt] = *(const bf16x8*)(abase + mt * (16 * CC) + ks * 32);
#pragma unroll
        for (int ot = 0; ot < 4; ++ot) {
            const int o = ot * 16 + ln;
            const int gr = (ks * 4 + q) ^ ln;          // swizzled granule
            bfr[ot] = *(const bf16x8*)(&Wt[o * CC + gr * 8]);
        }
#pragma unroll
        for (int mt = 0; mt < 4; ++mt)
#pragma unroll
            for (int ot = 0; ot < 4; ++ot)
                acc[mt][ot] = __builtin_amdgcn_mfma_f32_16x16x32_bf16(
                    af[mt], bfr[ot], acc[mt][ot], 0, 0, 0);
    }

    // ---- Epilogue: per-wave LDS transpose -> wave-contiguous 1KB stores ----
    float* outbase = out + (((size_t)(b * LL + l)) * LL + mbase) * OO;
    float* sw = stile[wave];
#pragma unroll
    for (int mt = 0; mt < 4; ++mt) {
        // stage 16x64 tile (stride 68 -> 2-way banks), folding the +a4b3 bias
#pragma unroll
        for (int ot = 0; ot < 4; ++ot)
#pragma unroll
            for (int r = 0; r < 4; ++r)
                sw[(q * 4 + r) * 68 + ot * 16 + ln] = acc[mt][ot][r] + a4v[ot];
        // wave-private: compiler orders via lgkmcnt; store 4x dwordx4 = 1KB/instr
#pragma unroll
        for (int i = 0; i < 4; ++i) {
            const int idx = i * 64 + lane;       // float4 index within 16x64 tile
            const int row = idx >> 4;
            const int col = (idx & 15) * 4;
            const float4 v = *(const float4*)(sw + row * 68 + col);
            *(float4*)(outbase + (mt * 16 + row) * OO + col) = v;
        }
    }
}

extern "C" void kernel_launch(void* const* d_in, const int* in_sizes, int n_in,
                              void* d_out, int out_size, void* d_ws, size_t ws_size,
                              hipStream_t stream) {
    const float* x     = (const float*)d_in[0];
    const float* gamma = (const float*)d_in[1];
    const float* beta  = (const float*)d_in[2];
    const float* w1    = (const float*)d_in[3];
    const float* b1    = (const float*)d_in[4];
    const float* w2    = (const float*)d_in[5];
    const float* b2    = (const float*)d_in[6];
    const float* w3    = (const float*)d_in[7];
    const float* b3    = (const float*)d_in[8];
    const float* w4    = (const float*)d_in[9];
    float* out = (float*)d_out;

    char* ws = (char*)d_ws;
    float* a_ws            = (float*)ws;                       // B*L*C fp32  = 512 KB
    __hip_bfloat16* bact   = (__hip_bfloat16*)(ws + 512*1024); // B*L*C bf16  = 256 KB
    float* a4b3_ws         = (float*)(ws + 768*1024);          // B*L*O fp32  = 256 KB
    float* w3t_ws          = (float*)(ws + 1024*1024);         // O*C fp32    = 32 KB
    float* w4t_ws          = (float*)(ws + 1024*1024 + 32*1024); // O*C fp32  = 32 KB

    prep_kernel<<<BB * LL, 256, 0, stream>>>(x, gamma, beta, w1, b1, w2, b2,
                                             w4, b3, w3,
                                             a_ws, bact, a4b3_ws, w3t_ws, w4t_ws);
    main_kernel<<<BB * LL * 2, 256, 0, stream>>>(a_ws, bact, a4b3_ws,
                                                 w3t_ws, w4t_ws, out);
}